// Round 1
// baseline (5919.064 us; speedup 1.0000x reference)
//
#include <hip/hip_runtime.h>

#define DD 128

// ---------------- degree / norm ----------------

__global__ void k_init_deg(float* __restrict__ deg, int N) {
    int i = blockIdx.x * 256 + threadIdx.x;
    if (i < N) deg[i] = 1.0f;   // self-loop
}

__global__ void k_count_deg(const int* __restrict__ dst, float* __restrict__ deg, int E) {
    int e = blockIdx.x * 256 + threadIdx.x;
    if (e < E) atomicAdd(&deg[dst[e]], 1.0f);
}

__global__ void k_dinv(const float* __restrict__ deg, float* __restrict__ dinv, int N) {
    int i = blockIdx.x * 256 + threadIdx.x;
    if (i < N) dinv[i] = rsqrtf(deg[i]);
}

// ---------------- dense h = x @ W^T  (fp32, VALU) ----------------
// block: 256 threads -> tile of 32 nodes x 128 cols, one matrix m = blockIdx.y
// writes h (workspace) and initializes out = h*dinv^2 + b (self-loop + bias)

__global__ __launch_bounds__(256) void k_gemm(
    const float* __restrict__ x0, const float* __restrict__ x1,
    const float* __restrict__ x2, const float* __restrict__ x3,
    const float* __restrict__ W1, const float* __restrict__ W2,
    const float* __restrict__ b1, const float* __restrict__ b2,
    const float* __restrict__ dinv,
    float* __restrict__ h, float* __restrict__ out, int N)
{
    const int m = blockIdx.y;
    const float* x  = (m == 0) ? x0 : (m == 1) ? x1 : (m == 2) ? x2 : x3;
    const float* W  = (m & 1) ? W2 : W1;   // m=0(r1),2(i1) -> W1 ; m=1(r2),3(i2) -> W2
    const float* bb = (m & 1) ? b2 : b1;
    float* hm = h   + (size_t)m * N * DD;
    float* om = out + (size_t)m * N * DD;

    __shared__ float xs[32][DD + 4];
    const int n0  = blockIdx.x * 32;
    const int tid = threadIdx.x;

    // stage x tile (32 rows x 128 cols), coalesced float4
    for (int t = tid; t < 32 * 32; t += 256) {
        int row = t >> 5, c4 = t & 31;
        int n = n0 + row;
        float4 v = make_float4(0.f, 0.f, 0.f, 0.f);
        if (n < N) v = ((const float4*)(x + (size_t)n * DD))[c4];
        *((float4*)&xs[row][c4 * 4]) = v;
    }
    __syncthreads();

    const int c0 = (tid & 31) * 4;   // 32 col-groups x 4 cols = 128 cols
    const int r0 = (tid >> 5) * 4;   // 8 row-groups x 4 rows = 32 rows

    float acc[4][4] = {};
    for (int k4 = 0; k4 < DD / 4; ++k4) {
        float4 xv[4], wv[4];
#pragma unroll
        for (int i = 0; i < 4; ++i)
            xv[i] = *((const float4*)&xs[r0 + i][k4 * 4]);   // broadcast within half-wave
#pragma unroll
        for (int j = 0; j < 4; ++j)
            wv[j] = ((const float4*)(W + (size_t)(c0 + j) * DD))[k4];  // L1-resident
#pragma unroll
        for (int i = 0; i < 4; ++i)
#pragma unroll
            for (int j = 0; j < 4; ++j)
                acc[i][j] += xv[i].x * wv[j].x + xv[i].y * wv[j].y +
                             xv[i].z * wv[j].z + xv[i].w * wv[j].w;
    }

    const float4 bv = *((const float4*)(bb + c0));
#pragma unroll
    for (int i = 0; i < 4; ++i) {
        int n = n0 + r0 + i;
        if (n >= N) continue;
        float dv = dinv[n];
        float sn = dv * dv;          // self-loop norm = 1/deg
        float4 hv = make_float4(acc[i][0], acc[i][1], acc[i][2], acc[i][3]);
        *((float4*)(hm + (size_t)n * DD + c0)) = hv;
        float4 ov = make_float4(hv.x * sn + bv.x, hv.y * sn + bv.y,
                                hv.z * sn + bv.z, hv.w * sn + bv.w);
        *((float4*)(om + (size_t)n * DD + c0)) = ov;
    }
}

// ---------------- edge scatter: out[dst] += h[src] * norm ----------------
// 32 threads per edge, each thread: 4 cols x 4 matrices

__global__ __launch_bounds__(256) void k_scatter(
    const int* __restrict__ ei, const float* __restrict__ dinv,
    const float* __restrict__ h, float* __restrict__ out, int N, int E)
{
    long long t = (long long)blockIdx.x * 256 + threadIdx.x;
    int e = (int)(t >> 5);
    if (e >= E) return;
    int cq = ((int)t & 31) * 4;

    int src = ei[e];
    int dst = ei[E + e];
    float norm = dinv[src] * dinv[dst];

#pragma unroll
    for (int m = 0; m < 4; ++m) {
        const float4 v = *((const float4*)(h + ((size_t)m * N + src) * DD + cq));
        float* o = out + ((size_t)m * N + dst) * DD + cq;
        atomicAdd(o + 0, v.x * norm);
        atomicAdd(o + 1, v.y * norm);
        atomicAdd(o + 2, v.z * norm);
        atomicAdd(o + 3, v.w * norm);
    }
}

// ---------------- launch ----------------

extern "C" void kernel_launch(void* const* d_in, const int* in_sizes, int n_in,
                              void* d_out, int out_size, void* d_ws, size_t ws_size,
                              hipStream_t stream) {
    const float* x0 = (const float*)d_in[0];
    const float* x1 = (const float*)d_in[1];
    const float* x2 = (const float*)d_in[2];
    const float* x3 = (const float*)d_in[3];
    const int*   ei = (const int*)d_in[4];
    const float* W1 = (const float*)d_in[5];
    const float* b1 = (const float*)d_in[6];
    const float* W2 = (const float*)d_in[7];
    const float* b2 = (const float*)d_in[8];
    float* out = (float*)d_out;

    const int N = in_sizes[0] / DD;   // 50000
    const int E = in_sizes[4] / 2;    // 800000

    float* deg  = (float*)d_ws;
    float* dinv = deg + 65536;
    float* h    = deg + 131072;       // 4 * N * 128 floats = 102.4 MB

    k_init_deg<<<(N + 255) / 256, 256, 0, stream>>>(deg, N);
    k_count_deg<<<(E + 255) / 256, 256, 0, stream>>>(ei + E, deg, E);
    k_dinv<<<(N + 255) / 256, 256, 0, stream>>>(deg, dinv, N);

    dim3 g((N + 31) / 32, 4);
    k_gemm<<<g, 256, 0, stream>>>(x0, x1, x2, x3, W1, W2, b1, b2, dinv, h, out, N);

    long long tot = (long long)E * 32;
    k_scatter<<<(int)((tot + 255) / 256), 256, 0, stream>>>(ei, dinv, h, out, N, E);
}

// Round 2
// 945.459 us; speedup vs baseline: 6.2605x; 6.2605x over previous
//
#include <hip/hip_runtime.h>

#define DD 128

// ---------------- CSR build ----------------

__global__ void k_zero(int* __restrict__ p, int n) {
    int i = blockIdx.x * 256 + threadIdx.x;
    if (i < n) p[i] = 0;
}

__global__ void k_count(const int* __restrict__ dst, int* __restrict__ cnt, int E) {
    int e = blockIdx.x * 256 + threadIdx.x;
    if (e < E) atomicAdd(&cnt[dst[e]], 1);
}

// single-block exclusive scan: rp[0]=0, rp[i+1]=sum(cnt[0..i])
__global__ __launch_bounds__(1024) void k_scan(const int* __restrict__ cnt,
                                               int* __restrict__ rp, int N) {
    __shared__ int buf[1024];
    const int tid = threadIdx.x;
    int carry = 0;
    for (int base = 0; base < N; base += 1024) {
        int i = base + tid;
        int v = (i < N) ? cnt[i] : 0;
        buf[tid] = v;
        __syncthreads();
        for (int off = 1; off < 1024; off <<= 1) {
            int t = (tid >= off) ? buf[tid - off] : 0;
            __syncthreads();
            buf[tid] += t;
            __syncthreads();
        }
        int inc = buf[tid];          // inclusive scan of this chunk
        int total = buf[1023];
        if (i < N) rp[i + 1] = carry + inc;
        carry += total;
        __syncthreads();
    }
    if (tid == 0) rp[0] = 0;
}

__global__ void k_dinv(const int* __restrict__ cnt, float* __restrict__ dinv, int N) {
    int i = blockIdx.x * 256 + threadIdx.x;
    if (i < N) dinv[i] = rsqrtf((float)(cnt[i] + 1));   // +1 self-loop
}

__global__ void k_fill(const int* __restrict__ ei, const int* __restrict__ rp,
                       int* __restrict__ cursor, const float* __restrict__ dinv,
                       int* __restrict__ csr_src, float* __restrict__ csr_w, int E) {
    int e = blockIdx.x * 256 + threadIdx.x;
    if (e >= E) return;
    int s = ei[e], d = ei[E + e];
    int pos = rp[d] + atomicAdd(&cursor[d], 1);
    csr_src[pos] = s;
    csr_w[pos] = dinv[s];
}

// ---------------- dense h = x @ W^T  (fp32, VALU) ----------------
// block: 256 threads -> tile of 32 nodes x 128 cols, one matrix m = blockIdx.y

__global__ __launch_bounds__(256) void k_gemm(
    const float* __restrict__ x0, const float* __restrict__ x1,
    const float* __restrict__ x2, const float* __restrict__ x3,
    const float* __restrict__ W1, const float* __restrict__ W2,
    float* __restrict__ h, int N)
{
    const int m = blockIdx.y;
    const float* x = (m == 0) ? x0 : (m == 1) ? x1 : (m == 2) ? x2 : x3;
    const float* W = (m & 1) ? W2 : W1;   // m=0,2 -> W1 ; m=1,3 -> W2
    float* hm = h + (size_t)m * N * DD;

    __shared__ float xs[32][DD + 4];
    const int n0  = blockIdx.x * 32;
    const int tid = threadIdx.x;

    for (int t = tid; t < 32 * 32; t += 256) {
        int row = t >> 5, c4 = t & 31;
        int n = n0 + row;
        float4 v = make_float4(0.f, 0.f, 0.f, 0.f);
        if (n < N) v = ((const float4*)(x + (size_t)n * DD))[c4];
        *((float4*)&xs[row][c4 * 4]) = v;
    }
    __syncthreads();

    const int c0 = (tid & 31) * 4;
    const int r0 = (tid >> 5) * 4;

    float acc[4][4] = {};
    for (int k4 = 0; k4 < DD / 4; ++k4) {
        float4 xv[4], wv[4];
#pragma unroll
        for (int i = 0; i < 4; ++i)
            xv[i] = *((const float4*)&xs[r0 + i][k4 * 4]);
#pragma unroll
        for (int j = 0; j < 4; ++j)
            wv[j] = ((const float4*)(W + (size_t)(c0 + j) * DD))[k4];
#pragma unroll
        for (int i = 0; i < 4; ++i)
#pragma unroll
            for (int j = 0; j < 4; ++j)
                acc[i][j] += xv[i].x * wv[j].x + xv[i].y * wv[j].y +
                             xv[i].z * wv[j].z + xv[i].w * wv[j].w;
    }

#pragma unroll
    for (int i = 0; i < 4; ++i) {
        int n = n0 + r0 + i;
        if (n >= N) continue;
        *((float4*)(hm + (size_t)n * DD + c0)) =
            make_float4(acc[i][0], acc[i][1], acc[i][2], acc[i][3]);
    }
}

// ---------------- aggregation: gather by dst via CSR ----------------
// one block (256 thr) per node; wave w = matrix w; each lane owns 2 cols

__global__ __launch_bounds__(256) void k_gather(
    const int* __restrict__ rp, const int* __restrict__ csr_src,
    const float* __restrict__ csr_w, const float* __restrict__ dinv,
    const float* __restrict__ h,
    const float* __restrict__ b1, const float* __restrict__ b2,
    float* __restrict__ out, int N)
{
    const int n = blockIdx.x;
    const int m = threadIdx.x >> 6;
    const int c = (threadIdx.x & 63) * 2;
    const float* bb = (m & 1) ? b2 : b1;
    const float* hm = h + (size_t)m * N * DD;

    const float dn = dinv[n];
    const float sn = dn * dn;                     // self-loop norm = 1/deg
    float2 hv = *(const float2*)(hm + (size_t)n * DD + c);
    float2 bv = *(const float2*)(bb + c);
    float ax = hv.x * sn + bv.x;
    float ay = hv.y * sn + bv.y;

    const int j1 = rp[n + 1];
    int j = rp[n];
    for (; j + 4 <= j1; j += 4) {
        int s0 = csr_src[j], s1 = csr_src[j + 1], s2 = csr_src[j + 2], s3 = csr_src[j + 3];
        float w0 = csr_w[j] * dn, w1 = csr_w[j + 1] * dn,
              w2 = csr_w[j + 2] * dn, w3 = csr_w[j + 3] * dn;
        float2 v0 = *(const float2*)(hm + (size_t)s0 * DD + c);
        float2 v1 = *(const float2*)(hm + (size_t)s1 * DD + c);
        float2 v2 = *(const float2*)(hm + (size_t)s2 * DD + c);
        float2 v3 = *(const float2*)(hm + (size_t)s3 * DD + c);
        ax += v0.x * w0 + v1.x * w1 + v2.x * w2 + v3.x * w3;
        ay += v0.y * w0 + v1.y * w1 + v2.y * w2 + v3.y * w3;
    }
    for (; j < j1; ++j) {
        int s = csr_src[j];
        float w = csr_w[j] * dn;
        float2 v = *(const float2*)(hm + (size_t)s * DD + c);
        ax += v.x * w;
        ay += v.y * w;
    }

    *(float2*)(out + ((size_t)m * N + n) * DD + c) = make_float2(ax, ay);
}

// ---------------- launch ----------------

extern "C" void kernel_launch(void* const* d_in, const int* in_sizes, int n_in,
                              void* d_out, int out_size, void* d_ws, size_t ws_size,
                              hipStream_t stream) {
    const float* x0 = (const float*)d_in[0];
    const float* x1 = (const float*)d_in[1];
    const float* x2 = (const float*)d_in[2];
    const float* x3 = (const float*)d_in[3];
    const int*   ei = (const int*)d_in[4];
    const float* W1 = (const float*)d_in[5];
    const float* b1 = (const float*)d_in[6];
    const float* W2 = (const float*)d_in[7];
    const float* b2 = (const float*)d_in[8];
    float* out = (float*)d_out;

    const int N = in_sizes[0] / DD;   // 50000
    const int E = in_sizes[4] / 2;    // 800000

    // workspace layout
    int*   cnt     = (int*)d_ws;                 // 65536
    int*   rp      = cnt + 65536;                // 65536 (needs N+1)
    int*   cursor  = rp + 65536;                 // 65536
    float* dinv    = (float*)(cursor + 65536);   // 65536
    int*   csr_src = (int*)(dinv + 65536);       // E
    float* csr_w   = (float*)(csr_src + E);      // E
    float* h       = csr_w + E;                  // 4*N*128 floats = 102.4 MB

    k_zero<<<(2 * 65536 + 255) / 256, 256, 0, stream>>>(cnt, 2 * 65536); // cnt+rp... zero cnt & rp region
    // (cursor zeroed separately)
    k_zero<<<(65536 + 255) / 256, 256, 0, stream>>>(cursor, 65536);

    k_count<<<(E + 255) / 256, 256, 0, stream>>>(ei + E, cnt, E);
    k_scan<<<1, 1024, 0, stream>>>(cnt, rp, N);
    k_dinv<<<(N + 255) / 256, 256, 0, stream>>>(cnt, dinv, N);
    k_fill<<<(E + 255) / 256, 256, 0, stream>>>(ei, rp, cursor, dinv, csr_src, csr_w, E);

    dim3 g((N + 31) / 32, 4);
    k_gemm<<<g, 256, 0, stream>>>(x0, x1, x2, x3, W1, W2, h, N);

    k_gather<<<N, 256, 0, stream>>>(rp, csr_src, csr_w, dinv, h, b1, b2, out, N);
}

// Round 3
// 607.021 us; speedup vs baseline: 9.7510x; 1.5575x over previous
//
#include <hip/hip_runtime.h>

#define DD 128

typedef __bf16 bf16x8 __attribute__((ext_vector_type(8)));
typedef float f32x4 __attribute__((ext_vector_type(4)));

static __device__ __forceinline__ unsigned short f2bf(float f) {
    unsigned int u = __float_as_uint(f);
    u += 0x7FFF + ((u >> 16) & 1);   // round-to-nearest-even
    return (unsigned short)(u >> 16);
}

// ---------------- CSR build ----------------

__global__ void k_zero(int* __restrict__ p, int n) {
    int i = blockIdx.x * 256 + threadIdx.x;
    if (i < n) p[i] = 0;
}

__global__ void k_count(const int* __restrict__ dst, int* __restrict__ cnt, int E) {
    int e = blockIdx.x * 256 + threadIdx.x;
    if (e < E) atomicAdd(&cnt[dst[e]], 1);
}

// exclusive scan, single block, wave-shfl based
__global__ __launch_bounds__(1024) void k_scan(const int* __restrict__ cnt,
                                               int* __restrict__ rp, int N) {
    __shared__ int wsum[16];
    const int tid = threadIdx.x, lane = tid & 63, wid = tid >> 6;
    int carry = 0;
    for (int base = 0; base < N; base += 1024) {
        int i = base + tid;
        int s = (i < N) ? cnt[i] : 0;
        // inclusive wave scan
        for (int off = 1; off < 64; off <<= 1) {
            int t = __shfl_up(s, off, 64);
            if (lane >= off) s += t;
        }
        if (lane == 63) wsum[wid] = s;
        __syncthreads();
        int woff = 0, total = 0;
#pragma unroll
        for (int w2 = 0; w2 < 16; ++w2) {
            int t = wsum[w2];
            if (w2 < wid) woff += t;
            total += t;
        }
        if (i < N) rp[i + 1] = carry + woff + s;
        carry += total;
        __syncthreads();
    }
    if (tid == 0) rp[0] = 0;
}

__global__ void k_dinv(const int* __restrict__ cnt, float* __restrict__ dinv, int N) {
    int i = blockIdx.x * 256 + threadIdx.x;
    if (i < N) dinv[i] = rsqrtf((float)(cnt[i] + 1));   // +1 self-loop
}

__global__ void k_fill(const int* __restrict__ ei, const int* __restrict__ rp,
                       int* __restrict__ cursor, const float* __restrict__ dinv,
                       int* __restrict__ csr_src, float* __restrict__ csr_w, int E) {
    int e = blockIdx.x * 256 + threadIdx.x;
    if (e >= E) return;
    int s = ei[e], d = ei[E + e];
    int pos = rp[d] + atomicAdd(&cursor[d], 1);
    csr_src[pos] = s;
    csr_w[pos] = dinv[s];
}

// ---------------- dense h = x @ W^T  (bf16 MFMA, fp32 accum) ----------------
// block 256 thr = 4 waves; tile 64 nodes x 128 cols; matrix m = blockIdx.y
// wave w computes rows [w*16, w*16+16) x all 128 cols = 8 MFMA tiles

__global__ __launch_bounds__(256) void k_gemm(
    const float* __restrict__ x0, const float* __restrict__ x1,
    const float* __restrict__ x2, const float* __restrict__ x3,
    const float* __restrict__ W1, const float* __restrict__ W2,
    float* __restrict__ h, int N)
{
    const int m = blockIdx.y;
    const float* x = (m == 0) ? x0 : (m == 1) ? x1 : (m == 2) ? x2 : x3;
    const float* W = (m & 1) ? W2 : W1;   // m=0,2 -> W1 ; m=1,3 -> W2
    float* hm = h + (size_t)m * N * DD;

    __shared__ unsigned short Ws[128 * 128];   // [c][k] bf16, 32 KB
    __shared__ unsigned short xs[64 * 128];    // [r][k] bf16, 16 KB

    const int tid = threadIdx.x;
    const int n0 = blockIdx.x * 64;

    // stage W -> bf16 LDS (16384 elems, 16 float4/thread)
    for (int t = tid; t < 128 * 128 / 4; t += 256) {
        float4 v = ((const float4*)W)[t];
        ushort4 b;
        b.x = f2bf(v.x); b.y = f2bf(v.y); b.z = f2bf(v.z); b.w = f2bf(v.w);
        *(ushort4*)&Ws[t * 4] = b;
    }
    // stage x tile -> bf16 LDS (64 rows x 128 cols)
    for (int t = tid; t < 64 * 128 / 4; t += 256) {
        int r = t >> 5;
        int n = n0 + r;
        float4 v = make_float4(0.f, 0.f, 0.f, 0.f);
        if (n < N) v = ((const float4*)(x + (size_t)n * DD))[t & 31];
        ushort4 b;
        b.x = f2bf(v.x); b.y = f2bf(v.y); b.z = f2bf(v.z); b.w = f2bf(v.w);
        *(ushort4*)&xs[t * 4] = b;
    }
    __syncthreads();

    const int w    = tid >> 6;
    const int lane = tid & 63;
    const int am   = lane & 15;        // A row / B col within 16-tile
    const int aq   = lane >> 4;        // quad -> k sub-block
    const int r0   = w * 16;

    f32x4 acc[8] = {};
#pragma unroll
    for (int kk = 0; kk < 128; kk += 32) {
        bf16x8 af = *(const bf16x8*)&xs[(r0 + am) * 128 + kk + aq * 8];
#pragma unroll
        for (int ct = 0; ct < 8; ++ct) {
            bf16x8 bf = *(const bf16x8*)&Ws[(ct * 16 + am) * 128 + kk + aq * 8];
            acc[ct] = __builtin_amdgcn_mfma_f32_16x16x32_bf16(af, bf, acc[ct], 0, 0, 0);
        }
    }

    // C/D layout: col = lane&15, row = (lane>>4)*4 + reg
    const int cc = lane & 15;
    const int rr = (lane >> 4) * 4;
#pragma unroll
    for (int ct = 0; ct < 8; ++ct) {
#pragma unroll
        for (int i = 0; i < 4; ++i) {
            int n = n0 + r0 + rr + i;
            if (n < N) hm[(size_t)n * DD + ct * 16 + cc] = acc[ct][i];
        }
    }
}

// ---------------- aggregation: gather by dst via CSR ----------------
// one block per node; 8 groups of 32 lanes = 4 matrices x 2 edge partitions;
// lane owns 4 cols (float4); unroll 4 edges -> 8 edges in flight per matrix

__global__ __launch_bounds__(256) void k_gather(
    const int* __restrict__ rp, const int* __restrict__ csr_src,
    const float* __restrict__ csr_w, const float* __restrict__ dinv,
    const float* __restrict__ h,
    const float* __restrict__ b1, const float* __restrict__ b2,
    float* __restrict__ out, int N)
{
    const int n   = blockIdx.x;
    const int tid = threadIdx.x;
    const int g   = tid >> 5;
    const int m   = g & 3;
    const int p   = g >> 2;           // edge partition 0/1
    const int c   = (tid & 31) * 4;
    const float* hm = h + (size_t)m * N * DD;

    const float dn = dinv[n];
    float ax = 0.f, ay = 0.f, az = 0.f, aw = 0.f;

    if (p == 0) {   // self-loop + bias
        const float sn = dn * dn;
        const float* bb = (m & 1) ? b2 : b1;
        float4 hv = *(const float4*)(hm + (size_t)n * DD + c);
        float4 bv = *(const float4*)(bb + c);
        ax = hv.x * sn + bv.x; ay = hv.y * sn + bv.y;
        az = hv.z * sn + bv.z; aw = hv.w * sn + bv.w;
    }

    const int j1 = rp[n + 1];
    int j = rp[n] + p;                 // this partition: j, j+2, j+4, ...
    for (; j + 6 < j1; j += 8) {
        int   s0 = csr_src[j],     s1 = csr_src[j + 2],
              s2 = csr_src[j + 4], s3 = csr_src[j + 6];
        float w0 = csr_w[j] * dn,     w1 = csr_w[j + 2] * dn,
              w2 = csr_w[j + 4] * dn, w3 = csr_w[j + 6] * dn;
        float4 v0 = *(const float4*)(hm + (size_t)s0 * DD + c);
        float4 v1 = *(const float4*)(hm + (size_t)s1 * DD + c);
        float4 v2 = *(const float4*)(hm + (size_t)s2 * DD + c);
        float4 v3 = *(const float4*)(hm + (size_t)s3 * DD + c);
        ax += v0.x * w0 + v1.x * w1 + v2.x * w2 + v3.x * w3;
        ay += v0.y * w0 + v1.y * w1 + v2.y * w2 + v3.y * w3;
        az += v0.z * w0 + v1.z * w1 + v2.z * w2 + v3.z * w3;
        aw += v0.w * w0 + v1.w * w1 + v2.w * w2 + v3.w * w3;
    }
    for (; j < j1; j += 2) {
        int s = csr_src[j];
        float wgt = csr_w[j] * dn;
        float4 v = *(const float4*)(hm + (size_t)s * DD + c);
        ax += v.x * wgt; ay += v.y * wgt; az += v.z * wgt; aw += v.w * wgt;
    }

    __shared__ float part[4][DD];
    if (p == 1) {
        float4 t = make_float4(ax, ay, az, aw);
        *(float4*)&part[m][c] = t;
    }
    __syncthreads();
    if (p == 0) {
        float4 t = *(const float4*)&part[m][c];
        float4 o = make_float4(ax + t.x, ay + t.y, az + t.z, aw + t.w);
        *(float4*)(out + ((size_t)m * N + n) * DD + c) = o;
    }
}

// ---------------- launch ----------------

extern "C" void kernel_launch(void* const* d_in, const int* in_sizes, int n_in,
                              void* d_out, int out_size, void* d_ws, size_t ws_size,
                              hipStream_t stream) {
    const float* x0 = (const float*)d_in[0];
    const float* x1 = (const float*)d_in[1];
    const float* x2 = (const float*)d_in[2];
    const float* x3 = (const float*)d_in[3];
    const int*   ei = (const int*)d_in[4];
    const float* W1 = (const float*)d_in[5];
    const float* b1 = (const float*)d_in[6];
    const float* W2 = (const float*)d_in[7];
    const float* b2 = (const float*)d_in[8];
    float* out = (float*)d_out;

    const int N = in_sizes[0] / DD;   // 50000
    const int E = in_sizes[4] / 2;    // 800000

    // workspace layout (cnt and cursor adjacent for one zeroing pass)
    int*   cnt     = (int*)d_ws;                 // 65536
    int*   cursor  = cnt + 65536;                // 65536
    int*   rp      = cursor + 65536;             // 65536 (needs N+1)
    float* dinv    = (float*)(rp + 65536);       // 65536
    int*   csr_src = (int*)(dinv + 65536);       // E
    float* csr_w   = (float*)(csr_src + E);      // E
    float* h       = csr_w + E;                  // 4*N*128 floats = 102.4 MB

    k_zero<<<(2 * 65536 + 255) / 256, 256, 0, stream>>>(cnt, 2 * 65536);
    k_count<<<(E + 255) / 256, 256, 0, stream>>>(ei + E, cnt, E);
    k_scan<<<1, 1024, 0, stream>>>(cnt, rp, N);
    k_dinv<<<(N + 255) / 256, 256, 0, stream>>>(cnt, dinv, N);
    k_fill<<<(E + 255) / 256, 256, 0, stream>>>(ei, rp, cursor, dinv, csr_src, csr_w, E);

    dim3 g((N + 63) / 64, 4);
    k_gemm<<<g, 256, 0, stream>>>(x0, x1, x2, x3, W1, W2, h, N);

    k_gather<<<N, 256, 0, stream>>>(rp, csr_src, csr_w, dinv, h, b1, b2, out, N);
}

// Round 5
// 480.320 us; speedup vs baseline: 12.3232x; 1.2638x over previous
//
#include <hip/hip_runtime.h>

#define DD 128

typedef __bf16 bf16x8 __attribute__((ext_vector_type(8)));
typedef float f32x4 __attribute__((ext_vector_type(4)));

static __device__ __forceinline__ unsigned short f2bf(float f) {
    unsigned int u = __float_as_uint(f);
    u += 0x7FFF + ((u >> 16) & 1);   // round-to-nearest-even
    return (unsigned short)(u >> 16);
}
static __device__ __forceinline__ float bf2f(unsigned short v) {
    return __uint_as_float(((unsigned)v) << 16);
}

// ---------------- CSR build ----------------

__global__ void k_zero(int* __restrict__ p, int n) {
    int i = blockIdx.x * 256 + threadIdx.x;
    if (i < n) p[i] = 0;
}

__global__ void k_count(const int* __restrict__ dst, int* __restrict__ cnt, int E) {
    int e = blockIdx.x * 256 + threadIdx.x;
    if (e < E) atomicAdd(&cnt[dst[e]], 1);
}

// exclusive scan + dinv, single block, wave-shfl based
__global__ __launch_bounds__(1024) void k_scan(const int* __restrict__ cnt,
                                               int* __restrict__ rp,
                                               float* __restrict__ dinv, int N) {
    __shared__ int wsum[16];
    const int tid = threadIdx.x, lane = tid & 63, wid = tid >> 6;
    int carry = 0;
    for (int base = 0; base < N; base += 1024) {
        int i = base + tid;
        int v = (i < N) ? cnt[i] : 0;
        int s = v;
        for (int off = 1; off < 64; off <<= 1) {
            int t = __shfl_up(s, off, 64);
            if (lane >= off) s += t;
        }
        if (lane == 63) wsum[wid] = s;
        __syncthreads();
        int woff = 0, total = 0;
#pragma unroll
        for (int w2 = 0; w2 < 16; ++w2) {
            int t = wsum[w2];
            if (w2 < wid) woff += t;
            total += t;
        }
        if (i < N) {
            rp[i + 1] = carry + woff + s;
            dinv[i] = rsqrtf((float)(v + 1));   // +1 self-loop
        }
        carry += total;
        __syncthreads();
    }
    if (tid == 0) rp[0] = 0;
}

__global__ void k_fill(const int* __restrict__ ei, const int* __restrict__ rp,
                       int* __restrict__ cursor, const float* __restrict__ dinv,
                       int2* __restrict__ csr, int E) {
    int e = blockIdx.x * 256 + threadIdx.x;
    if (e >= E) return;
    int s = ei[e], d = ei[E + e];
    int pos = rp[d] + atomicAdd(&cursor[d], 1);
    csr[pos] = make_int2(s, __float_as_int(dinv[s]));
}

// ---------------- dense h = x @ W^T  (bf16 MFMA, fp32 accum, bf16 h out) ----
// block 256 thr = 4 waves; tile 64 nodes x 128 cols; matrix m = blockIdx.y

__global__ __launch_bounds__(256) void k_gemm(
    const float* __restrict__ x0, const float* __restrict__ x1,
    const float* __restrict__ x2, const float* __restrict__ x3,
    const float* __restrict__ W1, const float* __restrict__ W2,
    unsigned short* __restrict__ h, int N)
{
    const int m = blockIdx.y;
    const float* x = (m == 0) ? x0 : (m == 1) ? x1 : (m == 2) ? x2 : x3;
    const float* W = (m & 1) ? W2 : W1;   // m=0,2 -> W1 ; m=1,3 -> W2
    unsigned short* hm = h + (size_t)m * N * DD;

    __shared__ unsigned short Ws[128 * 128];   // [c][k] bf16, 32 KB
    __shared__ unsigned short ts[64 * 136];    // stage stride 128; epilogue stride 136

    const int tid = threadIdx.x;
    const int n0 = blockIdx.x * 64;

    // stage W -> bf16 LDS
    for (int t = tid; t < 128 * 128 / 4; t += 256) {
        float4 v = ((const float4*)W)[t];
        ushort4 b;
        b.x = f2bf(v.x); b.y = f2bf(v.y); b.z = f2bf(v.z); b.w = f2bf(v.w);
        *(ushort4*)&Ws[t * 4] = b;
    }
    // stage x tile -> bf16 LDS (64 rows x 128 cols, stride 128)
    for (int t = tid; t < 64 * 32; t += 256) {
        int r = t >> 5;
        int n = n0 + r;
        float4 v = make_float4(0.f, 0.f, 0.f, 0.f);
        if (n < N) v = ((const float4*)(x + (size_t)n * DD))[t & 31];
        ushort4 b;
        b.x = f2bf(v.x); b.y = f2bf(v.y); b.z = f2bf(v.z); b.w = f2bf(v.w);
        *(ushort4*)&ts[r * 128 + (t & 31) * 4] = b;
    }
    __syncthreads();

    const int w    = tid >> 6;
    const int lane = tid & 63;
    const int am   = lane & 15;
    const int aq   = lane >> 4;
    const int r0   = w * 16;

    f32x4 acc[8] = {};
#pragma unroll
    for (int kk = 0; kk < 128; kk += 32) {
        bf16x8 af = *(const bf16x8*)&ts[(r0 + am) * 128 + kk + aq * 8];
#pragma unroll
        for (int ct = 0; ct < 8; ++ct) {
            bf16x8 bf = *(const bf16x8*)&Ws[(ct * 16 + am) * 128 + kk + aq * 8];
            acc[ct] = __builtin_amdgcn_mfma_f32_16x16x32_bf16(af, bf, acc[ct], 0, 0, 0);
        }
    }
    __syncthreads();   // all waves done reading ts before epilogue overwrite

    // C/D layout: col = lane&15, row = (lane>>4)*4 + reg  -> bf16 into ts (stride 136)
    const int cc = lane & 15;
    const int rr = (lane >> 4) * 4;
#pragma unroll
    for (int ct = 0; ct < 8; ++ct)
#pragma unroll
        for (int i = 0; i < 4; ++i)
            ts[(r0 + rr + i) * 136 + ct * 16 + cc] = f2bf(acc[ct][i]);
    __syncthreads();

    // coalesced store: 64 rows x 16 chunks of 8 ushorts (16 B) = 1024 chunks, 4/thread
#pragma unroll
    for (int k = 0; k < 4; ++k) {
        int f = k * 256 + tid;
        int row = f >> 4, ch = f & 15;
        int n = n0 + row;
        if (n < N) {
            uint4 v = *(const uint4*)&ts[row * 136 + ch * 8];
            *(uint4*)(hm + (size_t)n * DD + ch * 8) = v;
        }
    }
}

// ---------------- aggregation: gather by dst via CSR (bf16 h) ----------------
// one block per node; 8 groups of 32 lanes = 4 matrices x 2 edge partitions;
// lane owns 4 cols (ushort4 = 8 B); unroll 4 edges per partition

__global__ __launch_bounds__(256) void k_gather(
    const int* __restrict__ rp, const int2* __restrict__ csr,
    const float* __restrict__ dinv, const unsigned short* __restrict__ h,
    const float* __restrict__ b1, const float* __restrict__ b2,
    float* __restrict__ out, int N)
{
    const int n   = blockIdx.x;
    const int tid = threadIdx.x;
    const int g   = tid >> 5;
    const int m   = g & 3;
    const int p   = g >> 2;
    const int c   = (tid & 31) * 4;
    const unsigned short* hm = h + (size_t)m * N * DD;

    const float dn = dinv[n];
    float ax = 0.f, ay = 0.f, az = 0.f, aw = 0.f;

    if (p == 0) {   // self-loop + bias
        const float sn = dn * dn;
        const float* bb = (m & 1) ? b2 : b1;
        ushort4 hv = *(const ushort4*)(hm + (size_t)n * DD + c);
        float4 bv = *(const float4*)(bb + c);
        ax = bf2f(hv.x) * sn + bv.x; ay = bf2f(hv.y) * sn + bv.y;
        az = bf2f(hv.z) * sn + bv.z; aw = bf2f(hv.w) * sn + bv.w;
    }

    const int j1 = rp[n + 1];
    int j = rp[n] + p;                 // this partition: j, j+2, j+4, ...
    for (; j + 6 < j1; j += 8) {
        int2 e0 = csr[j], e1 = csr[j + 2], e2 = csr[j + 4], e3 = csr[j + 6];
        float w0 = __int_as_float(e0.y) * dn, w1 = __int_as_float(e1.y) * dn,
              w2 = __int_as_float(e2.y) * dn, w3 = __int_as_float(e3.y) * dn;
        ushort4 v0 = *(const ushort4*)(hm + (size_t)e0.x * DD + c);
        ushort4 v1 = *(const ushort4*)(hm + (size_t)e1.x * DD + c);
        ushort4 v2 = *(const ushort4*)(hm + (size_t)e2.x * DD + c);
        ushort4 v3 = *(const ushort4*)(hm + (size_t)e3.x * DD + c);
        ax += bf2f(v0.x) * w0 + bf2f(v1.x) * w1 + bf2f(v2.x) * w2 + bf2f(v3.x) * w3;
        ay += bf2f(v0.y) * w0 + bf2f(v1.y) * w1 + bf2f(v2.y) * w2 + bf2f(v3.y) * w3;
        az += bf2f(v0.z) * w0 + bf2f(v1.z) * w1 + bf2f(v2.z) * w2 + bf2f(v3.z) * w3;
        aw += bf2f(v0.w) * w0 + bf2f(v1.w) * w1 + bf2f(v2.w) * w2 + bf2f(v3.w) * w3;
    }
    for (; j < j1; j += 2) {
        int2 e = csr[j];
        float wgt = __int_as_float(e.y) * dn;
        ushort4 v = *(const ushort4*)(hm + (size_t)e.x * DD + c);
        ax += bf2f(v.x) * wgt; ay += bf2f(v.y) * wgt;
        az += bf2f(v.z) * wgt; aw += bf2f(v.w) * wgt;
    }

    __shared__ float part[4][DD];
    if (p == 1) *(float4*)&part[m][c] = make_float4(ax, ay, az, aw);
    __syncthreads();
    if (p == 0) {
        float4 t = *(const float4*)&part[m][c];
        *(float4*)(out + ((size_t)m * N + n) * DD + c) =
            make_float4(ax + t.x, ay + t.y, az + t.z, aw + t.w);
    }
}

// ---------------- launch ----------------

extern "C" void kernel_launch(void* const* d_in, const int* in_sizes, int n_in,
                              void* d_out, int out_size, void* d_ws, size_t ws_size,
                              hipStream_t stream) {
    const float* x0 = (const float*)d_in[0];
    const float* x1 = (const float*)d_in[1];
    const float* x2 = (const float*)d_in[2];
    const float* x3 = (const float*)d_in[3];
    const int*   ei = (const int*)d_in[4];
    const float* W1 = (const float*)d_in[5];
    const float* b1 = (const float*)d_in[6];
    const float* W2 = (const float*)d_in[7];
    const float* b2 = (const float*)d_in[8];
    float* out = (float*)d_out;

    const int N = in_sizes[0] / DD;   // 50000
    const int E = in_sizes[4] / 2;    // 800000

    // workspace layout
    int*   cnt    = (int*)d_ws;                       // 65536
    int*   cursor = cnt + 65536;                      // 65536
    int*   rp     = cursor + 65536;                   // 65536 (needs N+1)
    float* dinv   = (float*)(rp + 65536);             // 65536
    int2*  csr    = (int2*)(dinv + 65536);            // E int2
    unsigned short* h = (unsigned short*)(csr + E);   // 4*N*128 bf16 = 51.2 MB

    k_zero<<<(2 * 65536 + 255) / 256, 256, 0, stream>>>(cnt, 2 * 65536);
    k_count<<<(E + 255) / 256, 256, 0, stream>>>(ei + E, cnt, E);
    k_scan<<<1, 1024, 0, stream>>>(cnt, rp, dinv, N);
    k_fill<<<(E + 255) / 256, 256, 0, stream>>>(ei, rp, cursor, dinv, csr, E);

    dim3 g((N + 63) / 64, 4);
    k_gemm<<<g, 256, 0, stream>>>(x0, x1, x2, x3, W1, W2, h, N);

    k_gather<<<N, 256, 0, stream>>>(rp, csr, dinv, h, b1, b2, out, N);
}